// Round 13
// baseline (145.441 us; speedup 1.0000x reference)
//
#include <hip/hip_runtime.h>
#include <hip/hip_bf16.h>

#define B_ 16
#define P_ 1024
#define T_ (B_*P_)
#define CH_ 32          // chunks per batch for the softmax scan
#define CL_ (P_/CH_)    // 32 positions per chunk

// ---- ws layout (floats). psi/phi weights staged f32; rho read raw in k45. ----
constexpr int OFF_A     = 16;                       // 95*4 + 4 = 384
constexpr int OFF_WPSI1 = 400;                      // 1984
constexpr int OFF_BPSI1 = OFF_WPSI1 + 1984;         // 64
constexpr int OFF_WPSI2 = OFF_BPSI1 + 64;           // 4096
constexpr int OFF_BPSI2 = OFF_WPSI2 + 4096;         // 64
constexpr int OFF_WPHI1 = OFF_BPSI2 + 64;           // 992
constexpr int OFF_BPHI1 = OFF_WPHI1 + 992;          // 32
constexpr int OFF_WPHI2 = OFF_BPHI1 + 32;           // 1024
constexpr int OFF_BPHI2 = OFF_WPHI2 + 1024;         // 32
constexpr int OFF_WRHO1 = OFF_BPHI2 + 32;           // (legacy, unused)
constexpr int OFF_BRHO1 = OFF_WRHO1 + 8192;
constexpr int OFF_WRHO2 = OFF_BRHO1 + 64;
constexpr int OFF_BRHO2 = OFF_WRHO2 + 4096;
constexpr int OFF_PHI   = OFF_BRHO2 + 64;           // T*32  phi*mask
constexpr int OFF_Z     = OFF_PHI   + T_*32;        // T*4   z = (psi*m).A2
constexpr int OFF_PREX  = OFF_Z     + T_*4;         // T*4
constexpr int OFF_EXPW  = OFF_PREX  + T_*4;         // T*4   e = exp(pre - Mc[b,ch,h])
constexpr int OFF_CE    = OFF_EXPW  + T_*4;         // B*CH*4 chunk E-sums (chunk-shifted)
constexpr int OFF_CS    = OFF_CE    + 2048;         // B*CH*128 chunk S-sums (chunk-shifted)
constexpr int OFF_CZ    = OFF_CS    + 65536;        // B*CH*8: chunk (m,z[4]) totals, pad 8
constexpr int OFF_CM    = OFF_CZ    + 4096;         // B*CH*4 chunk maxima

static __device__ __forceinline__ bool detect_f32(const void* mask_raw) {
  return ((*(const unsigned*)mask_raw) & 0xFFFFu) == 0u;
}
static __device__ __forceinline__ float ld_any(const void* src, int i, bool isf32) {
  if (isf32) return ((const float*)src)[i];
  return __bfloat162float(((const __hip_bfloat16*)src)[i]);
}
static __device__ __forceinline__ float bfbits(unsigned u) {
  union { unsigned q; float f; } x; x.q = u << 16; return x.f;
}

// ---------- S01: stage psi/phi weights to f32 (blocks >=2) + fold A (blocks 0..1) ----------
__global__ __launch_bounds__(256) void s01_prep(
    float* __restrict__ ws, const void* mask,
    const void* Wpsi1, const void* bpsi1, const void* Wpsi2, const void* bpsi2,
    const void* Wkey,  const void* bkey,  const void* query,
    const void* Wphi1, const void* bphi1, const void* Wphi2, const void* bphi2) {
  const bool isf32 = detect_f32(mask);
  if (blockIdx.x < 2) {
    const int gid = blockIdx.x * 256 + threadIdx.x;
    if (gid >= 384) return;
    const float inv_s = 0.17677669529663687f;
    const int h = gid & 3;
    const int j = gid >> 2;  // 0..95; 95 = bias row
    float s = 0.f;
    if (j < 95) {
      for (int d = 0; d < 32; ++d)
        s += ld_any(Wkey, j * 128 + h * 32 + d, isf32) * ld_any(query, h * 32 + d, isf32);
    } else {
      for (int d = 0; d < 32; ++d)
        s += ld_any(bkey, h * 32 + d, isf32) * ld_any(query, h * 32 + d, isf32);
    }
    ws[OFF_A + gid] = s * inv_s;  // A[j][h] at j*4+h; c0[h] at 380+h
    return;
  }
  const int g  = (blockIdx.x - 2) * 256 + threadIdx.x;
  const int gs = (gridDim.x - 2) * 256;
  auto st = [&](int off, const void* src, int n) {
    for (int i = g; i < n; i += gs) ws[off + i] = ld_any(src, i, isf32);
  };
  st(OFF_WPSI1, Wpsi1, 1984); st(OFF_BPSI1, bpsi1, 64);
  st(OFF_WPSI2, Wpsi2, 4096); st(OFF_BPSI2, bpsi2, 64);
  st(OFF_WPHI1, Wphi1, 992);  st(OFF_BPHI1, bphi1, 32);
  st(OFF_WPHI2, Wphi2, 1024); st(OFF_BPHI2, bphi2, 32);
}

// ---------- K1: 32 tokens/block (1024 thr) = exactly one (b,ch) chunk ----------
// Weights LDS-staged from contiguous f32 ws block. New: block writes its chunk's
// (m, z[4]) totals to CZ[blockIdx.x] -- exclusive owner, NO atomics.
__global__ __launch_bounds__(1024) void k1_token(float* __restrict__ ws,
                                                 const int* __restrict__ measp,
                                                 const void* __restrict__ times,
                                                 const void* __restrict__ values,
                                                 const void* __restrict__ mask) {
  __shared__ float sWS[8288];       // psi/phi weights (ws offsets minus 400)
  __shared__ float sh1[32][64];
  __shared__ float sg1[32][32];
  __shared__ float swz[16][5];      // per-wave chunk-total partials
  constexpr int LW1 = 0, LB1 = 1984, LW2 = 2048, LB2 = 6144;
  constexpr int LP1 = 6208, LQ1 = 7200, LP2 = 7232, LQ2 = 8256;
  const bool isf32 = detect_f32(mask);
  const int tid = threadIdx.x;
  const int wv  = __builtin_amdgcn_readfirstlane(tid >> 6);   // 0..15
  const int j   = tid & 63;
  const int ta  = blockIdx.x * 32 + wv * 2;
  const int tb  = ta + 1;

  const float tva = ld_any(times, ta, isf32),  tvb = ld_any(times, tb, isf32);
  const float vva = ld_any(values, ta, isf32), vvb = ld_any(values, tb, isf32);
  const float mva = ld_any(mask, ta, isf32),   mvb = ld_any(mask, tb, isf32);
  const int   mea = measp[ta],                 meb = measp[tb];

  {
    const float4* src = (const float4*)(ws + OFF_WPSI1);
    float4* dst = (float4*)sWS;
    for (int i = tid; i < 2072; i += 1024) dst[i] = src[i];
  }

  const float sea = (mea > 0) ? 1.f : 0.f;
  const float seb = (meb > 0) ? 1.f : 0.f;
  const int   mra = (mea > 0) ? (8 + mea) : 0;
  const int   mrb = (meb > 0) ? (8 + meb) : 0;

  float xa[9], xb[9];
  const float posv[4] = {1.f, 10.f, 100.f, 1000.f};
  #pragma unroll
  for (int k = 0; k < 4; ++k) {
    float s, c;
    __sincosf(tva / posv[k], &s, &c); xa[2*k] = s; xa[2*k+1] = c;
    __sincosf(tvb / posv[k], &s, &c); xb[2*k] = s; xb[2*k+1] = c;
  }
  xa[8] = vva; xb[8] = vvb;
  __syncthreads();   // staging complete

  // psi L1
  float h1a = sWS[LB1 + j], h1b = h1a;
  #pragma unroll
  for (int i = 0; i < 9; ++i) {
    const float w = sWS[LW1 + i * 64 + j];
    h1a = fmaf(xa[i], w, h1a);
    h1b = fmaf(xb[i], w, h1b);
  }
  h1a = fmaf(sea, sWS[LW1 + mra * 64 + j], h1a);
  h1b = fmaf(seb, sWS[LW1 + mrb * 64 + j], h1b);
  sh1[wv * 2 + 0][j] = fmaxf(h1a, 0.f);
  sh1[wv * 2 + 1][j] = fmaxf(h1b, 0.f);

  // phi L1, lanes 0..31
  if (j < 32) {
    float g1a = sWS[LQ1 + j], g1b = g1a;
    #pragma unroll
    for (int i = 0; i < 9; ++i) {
      const float w = sWS[LP1 + i * 32 + j];
      g1a = fmaf(xa[i], w, g1a);
      g1b = fmaf(xb[i], w, g1b);
    }
    g1a = fmaf(sea, sWS[LP1 + mra * 32 + j], g1a);
    g1b = fmaf(seb, sWS[LP1 + mrb * 32 + j], g1b);
    sg1[wv * 2 + 0][j] = fmaxf(g1a, 0.f);
    sg1[wv * 2 + 1][j] = fmaxf(g1b, 0.f);
  }
  __syncthreads();

  // psi L2
  float h2a = sWS[LB2 + j], h2b = h2a;
  #pragma unroll 8
  for (int i = 0; i < 64; ++i) {
    const float w = sWS[LW2 + i * 64 + j];
    h2a = fmaf(sh1[wv * 2 + 0][i], w, h2a);
    h2b = fmaf(sh1[wv * 2 + 1][i], w, h2b);
  }
  const float qa = fmaxf(h2a, 0.f) * mva;
  const float qb = fmaxf(h2b, 0.f) * mvb;

  // z[h] = sum_j q_j * A2[j][h]
  const float4 a2 = *(const float4*)(ws + OFF_A + (31 + j) * 4);
  float z0a = qa * a2.x, z1a = qa * a2.y, z2a = qa * a2.z, z3a = qa * a2.w;
  float z0b = qb * a2.x, z1b = qb * a2.y, z2b = qb * a2.z, z3b = qb * a2.w;
  #pragma unroll
  for (int off = 32; off; off >>= 1) {
    z0a += __shfl_xor(z0a, off, 64); z1a += __shfl_xor(z1a, off, 64);
    z2a += __shfl_xor(z2a, off, 64); z3a += __shfl_xor(z3a, off, 64);
    z0b += __shfl_xor(z0b, off, 64); z1b += __shfl_xor(z1b, off, 64);
    z2b += __shfl_xor(z2b, off, 64); z3b += __shfl_xor(z3b, off, 64);
  }
  if (j == 0) {
    float4 va; va.x = z0a; va.y = z1a; va.z = z2a; va.w = z3a;
    float4 vb; vb.x = z0b; vb.y = z1b; vb.z = z2b; vb.w = z3b;
    *(float4*)(ws + OFF_Z + (size_t)ta * 4) = va;
    *(float4*)(ws + OFF_Z + (size_t)tb * 4) = vb;
    swz[wv][0] = mva + mvb;
    swz[wv][1] = z0a + z0b; swz[wv][2] = z1a + z1b;
    swz[wv][3] = z2a + z2b; swz[wv][4] = z3a + z3b;
  }

  // phi L2 on lanes 0..31; pre_x on lanes 32..39
  if (j < 32) {
    float g2a = sWS[LQ2 + j], g2b = g2a;
    #pragma unroll 8
    for (int i = 0; i < 32; ++i) {
      const float w = sWS[LP2 + i * 32 + j];
      g2a = fmaf(sg1[wv * 2 + 0][i], w, g2a);
      g2b = fmaf(sg1[wv * 2 + 1][i], w, g2b);
    }
    ws[OFF_PHI + (size_t)ta * 32 + j] = fmaxf(g2a, 0.f) * mva;
    ws[OFF_PHI + (size_t)tb * 32 + j] = fmaxf(g2b, 0.f) * mvb;
  } else if (j < 40) {
    const bool sec = j >= 36;
    const int h = (j - 32) & 3;
    const float sel  = sec ? seb : sea;
    const int   mrow = sec ? mrb : mra;
    const int   t    = sec ? tb : ta;
    float pr = ws[OFF_A + 380 + h];
    #pragma unroll
    for (int i = 0; i < 9; ++i) {
      const float xi = sec ? xb[i] : xa[i];
      pr = fmaf(xi, ws[OFF_A + i * 4 + h], pr);
    }
    pr = fmaf(sel, ws[OFF_A + mrow * 4 + h], pr);
    ws[OFF_PREX + (size_t)t * 4 + h] = pr;
  }

  // chunk totals: this block IS chunk blockIdx.x -- exclusive write, no atomics
  __syncthreads();
  if (tid < 5) {
    float s = 0.f;
    #pragma unroll
    for (int w = 0; w < 16; ++w) s += swz[w][tid];
    ws[OFF_CZ + (size_t)blockIdx.x * 8 + tid] = s;
  }
}

// ---------- K2B: chunk-parallel scan -> pre -> chunk-max -> e; + chunk (E,S) sums ----------
// grid (CH_, B_), 128 threads. Replaces k2_scanz AND k4a. No atomics (CZ written
// exclusively by k1 blocks). Lanes 0-31: prefix over chunk totals + in-chunk scan.
__global__ __launch_bounds__(128) void k2b_scan(float* __restrict__ ws,
                                                const void* __restrict__ mask) {
  const int ch = blockIdx.x, b = blockIdx.y;
  const int tid = threadIdx.x;
  const bool isf32 = detect_f32(mask);
  __shared__ float sE[32][4];
  const int pbeg = ch * CL_;

  if (tid < 32) {
    const int p = tid;
    // prefix totals over chunks < ch (lane c2 holds chunk c2's totals)
    float pc = 0.f, p0 = 0.f, p1 = 0.f, p2 = 0.f, p3 = 0.f;
    if (p < ch) {
      const float* cz = ws + OFF_CZ + (size_t)(b * CH_ + p) * 8;
      pc = cz[0]; p0 = cz[1]; p1 = cz[2]; p2 = cz[3]; p3 = cz[4];
    }
    #pragma unroll
    for (int mm = 16; mm; mm >>= 1) {
      pc += __shfl_xor(pc, mm, 32);
      p0 += __shfl_xor(p0, mm, 32);
      p1 += __shfl_xor(p1, mm, 32);
      p2 += __shfl_xor(p2, mm, 32);
      p3 += __shfl_xor(p3, mm, 32);
    }
    // own position's (m, z)
    const int tglob = b * P_ + pbeg + p;
    float c = ld_any(mask, tglob, isf32);
    const float4 zv = *(const float4*)(ws + OFF_Z + (size_t)tglob * 4);
    float z0 = zv.x, z1 = zv.y, z2 = zv.z, z3 = zv.w;
    // inclusive scan over the 32 positions
    #pragma unroll
    for (int off = 1; off < 32; off <<= 1) {
      const float uc = __shfl_up(c,  off, 32);
      const float u0 = __shfl_up(z0, off, 32);
      const float u1 = __shfl_up(z1, off, 32);
      const float u2 = __shfl_up(z2, off, 32);
      const float u3 = __shfl_up(z3, off, 32);
      if (p >= off) { c += uc; z0 += u0; z1 += u1; z2 += u2; z3 += u3; }
    }
    const float inv = 1.f / (pc + c);
    const float4 pxv = *(const float4*)(ws + OFF_PREX + (size_t)tglob * 4);
    const float pr0 = pxv.x + (p0 + z0) * inv;
    const float pr1 = pxv.y + (p1 + z1) * inv;
    const float pr2 = pxv.z + (p2 + z2) * inv;
    const float pr3 = pxv.w + (p3 + z3) * inv;
    // per-chunk max per head
    float m0 = pr0, m1 = pr1, m2 = pr2, m3 = pr3;
    #pragma unroll
    for (int mm = 16; mm; mm >>= 1) {
      m0 = fmaxf(m0, __shfl_xor(m0, mm, 32));
      m1 = fmaxf(m1, __shfl_xor(m1, mm, 32));
      m2 = fmaxf(m2, __shfl_xor(m2, mm, 32));
      m3 = fmaxf(m3, __shfl_xor(m3, mm, 32));
    }
    float4 ev;
    ev.x = __expf(pr0 - m0); ev.y = __expf(pr1 - m1);
    ev.z = __expf(pr2 - m2); ev.w = __expf(pr3 - m3);
    *(float4*)(ws + OFF_EXPW + (size_t)tglob * 4) = ev;
    sE[p][0] = ev.x; sE[p][1] = ev.y; sE[p][2] = ev.z; sE[p][3] = ev.w;
    if (p == 0) {
      float* cm = ws + OFF_CM + (size_t)(b * CH_ + ch) * 4;
      cm[0] = m0; cm[1] = m1; cm[2] = m2; cm[3] = m3;
    }
  }
  __syncthreads();

  // chunk sums of (e, e*phi) -- old k4a, e from LDS
  const int h = tid >> 5, d = tid & 31;
  const float* phiB = ws + OFF_PHI + (size_t)b * P_ * 32 + (size_t)pbeg * 32;
  float E = 0.f, S = 0.f;
  #pragma unroll 4
  for (int p = 0; p < 32; ++p) {
    const float e = sE[p][h];
    E += e;
    S = fmaf(e, phiB[p * 32 + d], S);
  }
  const int base = (b * CH_ + ch) * 4 + h;
  if (d == 0) ws[OFF_CE + base] = E;
  ws[OFF_CS + base * 32 + d] = S;
}

// ---------- K45: parallel phase-1 with max-merge -> combine -> rho MLP -> out ----------
// waves 0-1: local inclusive (E,S) of own chunk (Mown-shifted, from EXPW).
// waves 2-3: stage W_rho1; compute Mst + scaled prefix (E0,S0) over chunks < ch.
// combine: Et = E0 + fo*Eloc, St = S0 + fo*Sloc, fo = exp(Mown-Mst); shift cancels.
__global__ __launch_bounds__(256) void k45_fused(float* __restrict__ ws,
    const void* __restrict__ mask,
    const void* __restrict__ Wrho1, const void* __restrict__ brho1,
    const void* __restrict__ Wrho2, const void* __restrict__ brho2,
    void* __restrict__ out) {
  __shared__ float sW1[8192];       // 32 KB
  __shared__ float sAgg[32][128];   // 16 KB
  __shared__ float sH1[32][64];     //  8 KB
  __shared__ float sEloc[32][4];
  __shared__ float sPreS[128];
  __shared__ float sPreE[4];
  __shared__ float sFo[4];
  const int ch = blockIdx.x, b = blockIdx.y;
  const int tid = threadIdx.x;
  const bool isf32 = detect_f32(mask);
  const int pbeg = ch * CL_;

  if (tid < 128) {
    const int h = tid >> 5, d = tid & 31;
    const float* eB   = ws + OFF_EXPW + (size_t)b * P_ * 4;
    const float* phiB = ws + OFF_PHI  + (size_t)b * P_ * 32;
    float E = 0.f, S = 0.f;
    #pragma unroll 4
    for (int p = pbeg; p < pbeg + CL_; ++p) {
      const float e  = eB[p * 4 + h];
      const float ph = phiB[p * 32 + d];
      E += e;
      S = fmaf(e, ph, S);
      sAgg[p - pbeg][h * 32 + d] = S;            // unnormalized local S (Mown-shifted)
      if (d == 0) sEloc[p - pbeg][h] = E;        // local inclusive E
    }
  } else {
    const int tt = tid - 128;
    // stage W_rho1 (vectorized 16B loads)
    if (isf32) {
      const float4* w1 = (const float4*)Wrho1;  // 2048 float4
      for (int i = tt; i < 2048; i += 128) {
        const float4 v = w1[i];
        float* dst = sW1 + i * 4;
        dst[0] = v.x; dst[1] = v.y; dst[2] = v.z; dst[3] = v.w;
      }
    } else {
      const uint4* w1 = (const uint4*)Wrho1;    // 1024 uint4 = 8192 bf16
      for (int i = tt; i < 1024; i += 128) {
        const uint4 v = w1[i];
        float* dst = sW1 + i * 8;
        dst[0] = bfbits(v.x & 0xFFFFu); dst[1] = bfbits(v.x >> 16);
        dst[2] = bfbits(v.y & 0xFFFFu); dst[3] = bfbits(v.y >> 16);
        dst[4] = bfbits(v.z & 0xFFFFu); dst[5] = bfbits(v.z >> 16);
        dst[6] = bfbits(v.w & 0xFFFFu); dst[7] = bfbits(v.w >> 16);
      }
    }
    // max-merged prefix over earlier chunks (concurrent with local replay)
    const int h = tt >> 5, d = tt & 31;
    const float* cmB = ws + OFF_CM + (size_t)b * CH_ * 4;
    const float Mown = cmB[ch * 4 + h];
    float Mst = Mown;
    for (int c2 = 0; c2 < ch; ++c2) Mst = fmaxf(Mst, cmB[c2 * 4 + h]);
    float E0 = 0.f, S0 = 0.f;
    for (int c2 = 0; c2 < ch; ++c2) {
      const float f = __expf(cmB[c2 * 4 + h] - Mst);
      const int base2 = (b * CH_ + c2) * 4 + h;
      E0 = fmaf(ws[OFF_CE + base2], f, E0);
      S0 = fmaf(ws[OFF_CS + base2 * 32 + d], f, S0);
    }
    sPreS[tt] = S0;
    if (d == 0) { sPreE[h] = E0; sFo[h] = __expf(Mown - Mst); }
  }
  __syncthreads();

  // combine: 4096 slots / 256 threads = 16 each (stride-256, conflict-free)
  #pragma unroll
  for (int k = 0; k < 16; ++k) {
    const int slot = tid + k * 256;
    const int p = slot >> 7, c = slot & 127, h2 = c >> 5;
    const float fo = sFo[h2];
    const float Et = sPreE[h2] + fo * sEloc[p][h2];
    const float St = sPreS[c] + fo * sAgg[p][c];
    sAgg[p][c] = (St / Et) * ld_any(mask, b * P_ + pbeg + p, isf32);
  }
  __syncthreads();

  // phase 2: rho L1, each wave owns 8 tokens
  const int j = tid & 63, qw = tid >> 6;
  const float b1 = ld_any(brho1, j, isf32);
  float acc[8];
  #pragma unroll
  for (int k = 0; k < 8; ++k) acc[k] = b1;
  for (int i4 = 0; i4 < 32; ++i4) {
    const float w0 = sW1[(i4 * 4 + 0) * 64 + j];
    const float w1 = sW1[(i4 * 4 + 1) * 64 + j];
    const float w2 = sW1[(i4 * 4 + 2) * 64 + j];
    const float w3 = sW1[(i4 * 4 + 3) * 64 + j];
    #pragma unroll
    for (int k = 0; k < 8; ++k) {
      const float4 a = *(const float4*)&sAgg[qw * 8 + k][i4 * 4];
      acc[k] = fmaf(a.w, w3, fmaf(a.z, w2, fmaf(a.y, w1, fmaf(a.x, w0, acc[k]))));
    }
  }
  #pragma unroll
  for (int k = 0; k < 8; ++k) sH1[qw * 8 + k][j] = fmaxf(acc[k], 0.f);
  __syncthreads();

  // phase 3: rho L2
  const float b2 = ld_any(brho2, j, isf32);
  float o[8];
  #pragma unroll
  for (int k = 0; k < 8; ++k) o[k] = b2;
  if (isf32) {
    const float* W2 = (const float*)Wrho2;
    #pragma unroll 4
    for (int i = 0; i < 64; ++i) {
      const float w = W2[i * 64 + j];
      #pragma unroll
      for (int k = 0; k < 8; ++k) o[k] = fmaf(sH1[qw * 8 + k][i], w, o[k]);
    }
  } else {
    const __hip_bfloat16* W2 = (const __hip_bfloat16*)Wrho2;
    #pragma unroll 4
    for (int i = 0; i < 64; ++i) {
      const float w = __bfloat162float(W2[i * 64 + j]);
      #pragma unroll
      for (int k = 0; k < 8; ++k) o[k] = fmaf(sH1[qw * 8 + k][i], w, o[k]);
    }
  }

  const int t0 = b * P_ + pbeg + qw * 8;
  #pragma unroll
  for (int k = 0; k < 8; ++k) {
    const float mv = ld_any(mask, t0 + k, isf32);
    const float v  = fmaxf(o[k], 0.f) * mv;
    if (isf32) {
      ((float*)out)[(size_t)(t0 + k) * 64 + j] = v;
    } else {
      ((__hip_bfloat16*)out)[(size_t)(t0 + k) * 64 + j] = __float2bfloat16(v);
    }
  }
}

extern "C" void kernel_launch(void* const* d_in, const int* in_sizes, int n_in,
                              void* d_out, int out_size, void* d_ws, size_t ws_size,
                              hipStream_t stream) {
  const int* meas = (const int*)d_in[2];
  const void* times = d_in[0];
  const void* values = d_in[1];
  const void* mask = d_in[3];
  float* ws = (float*)d_ws;

  s01_prep<<<10, 256, 0, stream>>>(ws, mask,
                                   d_in[4], d_in[5], d_in[6], d_in[7],
                                   d_in[8], d_in[9], d_in[10],
                                   d_in[11], d_in[12], d_in[13], d_in[14]);
  k1_token<<<T_/32, 1024, 0, stream>>>(ws, meas, times, values, mask);
  k2b_scan<<<dim3(CH_, B_), 128, 0, stream>>>(ws, mask);
  k45_fused<<<dim3(CH_, B_), 256, 0, stream>>>(ws, mask,
                                               d_in[15], d_in[16], d_in[17], d_in[18],
                                               d_out);
}

// Round 16
// 141.659 us; speedup vs baseline: 1.0267x; 1.0267x over previous
//
#include <hip/hip_runtime.h>
#include <hip/hip_bf16.h>

#define B_ 16
#define P_ 1024
#define T_ (B_*P_)
#define CH_ 32          // chunks per batch for the softmax scan
#define CL_ (P_/CH_)    // 32 positions per chunk

// ---- ws layout (floats). psi/phi weights staged f32; rho read raw in k45. ----
constexpr int OFF_A     = 16;                       // 95*4 + 4 = 384
constexpr int OFF_WPSI1 = 400;                      // 1984
constexpr int OFF_BPSI1 = OFF_WPSI1 + 1984;         // 64
constexpr int OFF_WPSI2 = OFF_BPSI1 + 64;           // 4096
constexpr int OFF_BPSI2 = OFF_WPSI2 + 4096;         // 64
constexpr int OFF_WPHI1 = OFF_BPSI2 + 64;           // 992
constexpr int OFF_BPHI1 = OFF_WPHI1 + 992;          // 32
constexpr int OFF_WPHI2 = OFF_BPHI1 + 32;           // 1024
constexpr int OFF_BPHI2 = OFF_WPHI2 + 1024;         // 32
constexpr int OFF_WRHO1 = OFF_BPHI2 + 32;           // (legacy, unused)
constexpr int OFF_BRHO1 = OFF_WRHO1 + 8192;
constexpr int OFF_WRHO2 = OFF_BRHO1 + 64;
constexpr int OFF_BRHO2 = OFF_WRHO2 + 4096;
constexpr int OFF_PHI   = OFF_BRHO2 + 64;           // T*32  phi*mask
constexpr int OFF_Z     = OFF_PHI   + T_*32;        // T*4   z = (psi*m).A2
constexpr int OFF_PREX  = OFF_Z     + T_*4;         // T*4
constexpr int OFF_EXPW  = OFF_PREX  + T_*4;         // T*4   e = exp(pre - M[b,h])
constexpr int OFF_CE    = OFF_EXPW  + T_*4;         // B*CH*4 chunk E-sums
constexpr int OFF_CS    = OFF_CE    + 2048;         // B*CH*128 chunk S-sums

static __device__ __forceinline__ bool detect_f32(const void* mask_raw) {
  return ((*(const unsigned*)mask_raw) & 0xFFFFu) == 0u;
}
static __device__ __forceinline__ float ld_any(const void* src, int i, bool isf32) {
  if (isf32) return ((const float*)src)[i];
  return __bfloat162float(((const __hip_bfloat16*)src)[i]);
}
static __device__ __forceinline__ float bfbits(unsigned u) {
  union { unsigned q; float f; } x; x.q = u << 16; return x.f;
}

// ---------- S01: stage psi/phi weights to f32 (blocks >=2) + fold A (blocks 0..1) ----------
__global__ __launch_bounds__(256) void s01_prep(
    float* __restrict__ ws, const void* mask,
    const void* Wpsi1, const void* bpsi1, const void* Wpsi2, const void* bpsi2,
    const void* Wkey,  const void* bkey,  const void* query,
    const void* Wphi1, const void* bphi1, const void* Wphi2, const void* bphi2) {
  const bool isf32 = detect_f32(mask);
  if (blockIdx.x < 2) {
    const int gid = blockIdx.x * 256 + threadIdx.x;
    if (gid >= 384) return;
    const float inv_s = 0.17677669529663687f;
    const int h = gid & 3;
    const int j = gid >> 2;  // 0..95; 95 = bias row
    float s = 0.f;
    if (j < 95) {
      for (int d = 0; d < 32; ++d)
        s += ld_any(Wkey, j * 128 + h * 32 + d, isf32) * ld_any(query, h * 32 + d, isf32);
    } else {
      for (int d = 0; d < 32; ++d)
        s += ld_any(bkey, h * 32 + d, isf32) * ld_any(query, h * 32 + d, isf32);
    }
    ws[OFF_A + gid] = s * inv_s;  // A[j][h] at j*4+h; c0[h] at 380+h
    return;
  }
  const int g  = (blockIdx.x - 2) * 256 + threadIdx.x;
  const int gs = (gridDim.x - 2) * 256;
  auto st = [&](int off, const void* src, int n) {
    for (int i = g; i < n; i += gs) ws[off + i] = ld_any(src, i, isf32);
  };
  st(OFF_WPSI1, Wpsi1, 1984); st(OFF_BPSI1, bpsi1, 64);
  st(OFF_WPSI2, Wpsi2, 4096); st(OFF_BPSI2, bpsi2, 64);
  st(OFF_WPHI1, Wphi1, 992);  st(OFF_BPHI1, bphi1, 32);
  st(OFF_WPHI2, Wphi2, 1024); st(OFF_BPHI2, bphi2, 32);
}

// ---------- K1: 32 tokens/block (1024 thr), 2 tokens/wave, A+weights LDS-staged ----------
// Stages ws[16..8688) (A block + psi/phi weights, contiguous f32, 34.7KB) via float4,
// plus a conflict-free A2 transpose sA2T built from L2 during staging (no extra barrier).
// LDS ~46.9KB -> 2 blocks/CU x 16 waves = 32 waves/CU; grid 512 = exactly 2/CU.
__global__ __launch_bounds__(1024) void k1_token(float* __restrict__ ws,
                                                 const int* __restrict__ measp,
                                                 const void* __restrict__ times,
                                                 const void* __restrict__ values,
                                                 const void* __restrict__ mask) {
  __shared__ float sWS[8672];       // ws[16..8688): A at [0..384), weights after
  __shared__ float sA2T[256];       // sA2T[h*64+j] = A[31+j][h] (conflict-free z reads)
  __shared__ float sh1[32][64];
  __shared__ float sg1[32][32];
  constexpr int LA  = 0;
  constexpr int LW1 = 384,  LB1 = 2368, LW2 = 2432, LB2 = 6528;
  constexpr int LP1 = 6592, LQ1 = 7584, LP2 = 7616, LQ2 = 8640;
  const bool isf32 = detect_f32(mask);
  const int tid = threadIdx.x;
  const int wv  = __builtin_amdgcn_readfirstlane(tid >> 6);   // 0..15
  const int j   = tid & 63;
  const int ta  = blockIdx.x * 32 + wv * 2;
  const int tb  = ta + 1;

  // issue token-input loads early (resolve during staging)
  const float tva = ld_any(times, ta, isf32),  tvb = ld_any(times, tb, isf32);
  const float vva = ld_any(values, ta, isf32), vvb = ld_any(values, tb, isf32);
  const float mva = ld_any(mask, ta, isf32),   mvb = ld_any(mask, tb, isf32);
  const int   mea = measp[ta],                 meb = measp[tb];

  // stage A + weights: 2168 float4 across 1024 threads (~2 each)
  {
    const float4* src = (const float4*)(ws + OFF_A);
    float4* dst = (float4*)sWS;
    for (int i = tid; i < 2168; i += 1024) dst[i] = src[i];
  }
  // A2 transpose direct from L2 (independent of sWS; same barrier covers it)
  if (tid < 256) {
    const int h = tid >> 6, jj = tid & 63;
    sA2T[tid] = ws[OFF_A + (31 + jj) * 4 + h];
  }

  const float sea = (mea > 0) ? 1.f : 0.f;
  const float seb = (meb > 0) ? 1.f : 0.f;
  const int   mra = (mea > 0) ? (8 + mea) : 0;
  const int   mrb = (meb > 0) ? (8 + meb) : 0;

  float xa[9], xb[9];
  const float posv[4] = {1.f, 10.f, 100.f, 1000.f};
  #pragma unroll
  for (int k = 0; k < 4; ++k) {
    float s, c;
    __sincosf(tva / posv[k], &s, &c); xa[2*k] = s; xa[2*k+1] = c;
    __sincosf(tvb / posv[k], &s, &c); xb[2*k] = s; xb[2*k+1] = c;
  }
  xa[8] = vva; xb[8] = vvb;
  __syncthreads();   // staging complete

  // psi L1, channel j, both tokens
  float h1a = sWS[LB1 + j], h1b = h1a;
  #pragma unroll
  for (int i = 0; i < 9; ++i) {
    const float w = sWS[LW1 + i * 64 + j];
    h1a = fmaf(xa[i], w, h1a);
    h1b = fmaf(xb[i], w, h1b);
  }
  h1a = fmaf(sea, sWS[LW1 + mra * 64 + j], h1a);
  h1b = fmaf(seb, sWS[LW1 + mrb * 64 + j], h1b);
  sh1[wv * 2 + 0][j] = fmaxf(h1a, 0.f);
  sh1[wv * 2 + 1][j] = fmaxf(h1b, 0.f);

  // phi L1, lanes 0..31
  if (j < 32) {
    float g1a = sWS[LQ1 + j], g1b = g1a;
    #pragma unroll
    for (int i = 0; i < 9; ++i) {
      const float w = sWS[LP1 + i * 32 + j];
      g1a = fmaf(xa[i], w, g1a);
      g1b = fmaf(xb[i], w, g1b);
    }
    g1a = fmaf(sea, sWS[LP1 + mra * 32 + j], g1a);
    g1b = fmaf(seb, sWS[LP1 + mrb * 32 + j], g1b);
    sg1[wv * 2 + 0][j] = fmaxf(g1a, 0.f);
    sg1[wv * 2 + 1][j] = fmaxf(g1b, 0.f);
  }
  __syncthreads();

  // psi L2, both tokens
  float h2a = sWS[LB2 + j], h2b = h2a;
  #pragma unroll 8
  for (int i = 0; i < 64; ++i) {
    const float w = sWS[LW2 + i * 64 + j];
    h2a = fmaf(sh1[wv * 2 + 0][i], w, h2a);
    h2b = fmaf(sh1[wv * 2 + 1][i], w, h2b);
  }
  const float qa = fmaxf(h2a, 0.f) * mva;
  const float qb = fmaxf(h2b, 0.f) * mvb;

  // z[h] = sum_j q_j * A2[j][h] — butterfly over the wave (A2 from LDS, conflict-free)
  const float a20 = sA2T[0 * 64 + j], a21 = sA2T[1 * 64 + j];
  const float a22 = sA2T[2 * 64 + j], a23 = sA2T[3 * 64 + j];
  float z0a = qa * a20, z1a = qa * a21, z2a = qa * a22, z3a = qa * a23;
  float z0b = qb * a20, z1b = qb * a21, z2b = qb * a22, z3b = qb * a23;
  #pragma unroll
  for (int off = 32; off; off >>= 1) {
    z0a += __shfl_xor(z0a, off, 64); z1a += __shfl_xor(z1a, off, 64);
    z2a += __shfl_xor(z2a, off, 64); z3a += __shfl_xor(z3a, off, 64);
    z0b += __shfl_xor(z0b, off, 64); z1b += __shfl_xor(z1b, off, 64);
    z2b += __shfl_xor(z2b, off, 64); z3b += __shfl_xor(z3b, off, 64);
  }
  if (j == 0) {
    float4 va; va.x = z0a; va.y = z1a; va.z = z2a; va.w = z3a;
    float4 vb; vb.x = z0b; vb.y = z1b; vb.z = z2b; vb.w = z3b;
    *(float4*)(ws + OFF_Z + (size_t)ta * 4) = va;
    *(float4*)(ws + OFF_Z + (size_t)tb * 4) = vb;
  }

  // phi L2 on lanes 0..31; pre_x on lanes 32..39 (a: 32..35, b: 36..39)
  if (j < 32) {
    float g2a = sWS[LQ2 + j], g2b = g2a;
    #pragma unroll 8
    for (int i = 0; i < 32; ++i) {
      const float w = sWS[LP2 + i * 32 + j];
      g2a = fmaf(sg1[wv * 2 + 0][i], w, g2a);
      g2b = fmaf(sg1[wv * 2 + 1][i], w, g2b);
    }
    ws[OFF_PHI + (size_t)ta * 32 + j] = fmaxf(g2a, 0.f) * mva;
    ws[OFF_PHI + (size_t)tb * 32 + j] = fmaxf(g2b, 0.f) * mvb;
  } else if (j < 40) {
    const bool sec = j >= 36;
    const int h = (j - 32) & 3;
    const float sel  = sec ? seb : sea;
    const int   mrow = sec ? mrb : mra;
    const int   t    = sec ? tb : ta;
    float pr = sWS[LA + 380 + h];
    #pragma unroll
    for (int i = 0; i < 9; ++i) {
      const float xi = sec ? xb[i] : xa[i];
      pr = fmaf(xi, sWS[LA + i * 4 + h], pr);
    }
    pr = fmaf(sel, sWS[LA + mrow * 4 + h], pr);
    ws[OFF_PREX + (size_t)t * 4 + h] = pr;
  }
}

// ---------- K2: scan (cnt, z[4]) -> pre; batch-max per head; e = exp(pre-M) ----------
__global__ __launch_bounds__(256) void k2_scanz(float* __restrict__ ws,
                                                const void* __restrict__ mask) {
  const int b    = blockIdx.x;
  const int tid  = threadIdx.x;
  const int lane = tid & 63;
  const int wv   = tid >> 6;
  const bool isf32 = detect_f32(mask);
  __shared__ float swt[4][5];   // per-wave scan totals (c, z0..z3)
  __shared__ float smx[4][4];   // per-wave per-head maxima

  const float* zB = ws + OFF_Z + (size_t)b * P_ * 4;
  const int p0 = tid * 4;

  float lc[4], l0[4], l1[4], l2[4], l3[4];
  float c = 0.f, z0 = 0.f, z1 = 0.f, z2 = 0.f, z3 = 0.f;
  const float4* z4 = (const float4*)(zB + (size_t)p0 * 4);
  #pragma unroll
  for (int i = 0; i < 4; ++i) {
    const float4 zv = z4[i];
    c  += ld_any(mask, b * P_ + p0 + i, isf32);
    z0 += zv.x; z1 += zv.y; z2 += zv.z; z3 += zv.w;
    lc[i] = c; l0[i] = z0; l1[i] = z1; l2[i] = z2; l3[i] = z3;
  }

  float rc = c, r0 = z0, r1 = z1, r2 = z2, r3 = z3;
  #pragma unroll
  for (int off = 1; off < 64; off <<= 1) {
    const float uc = __shfl_up(rc, off, 64);
    const float u0 = __shfl_up(r0, off, 64);
    const float u1 = __shfl_up(r1, off, 64);
    const float u2 = __shfl_up(r2, off, 64);
    const float u3 = __shfl_up(r3, off, 64);
    if (lane >= off) { rc += uc; r0 += u0; r1 += u1; r2 += u2; r3 += u3; }
  }
  if (lane == 63) {
    swt[wv][0] = rc; swt[wv][1] = r0; swt[wv][2] = r1; swt[wv][3] = r2; swt[wv][4] = r3;
  }
  __syncthreads();
  #pragma unroll
  for (int w2 = 0; w2 < 3; ++w2) {
    if (wv > w2) {
      rc += swt[w2][0]; r0 += swt[w2][1]; r1 += swt[w2][2];
      r2 += swt[w2][3]; r3 += swt[w2][4];
    }
  }
  const float ec = rc - c, e0 = r0 - z0, e1 = r1 - z1, e2 = r2 - z2, e3 = r3 - z3;

  const float* px = ws + OFF_PREX + (size_t)b * P_ * 4;
  const float4* px4 = (const float4*)(px + (size_t)p0 * 4);
  float pre[4][4];
  float mx0 = -1e30f, mx1 = -1e30f, mx2 = -1e30f, mx3 = -1e30f;
  #pragma unroll
  for (int i = 0; i < 4; ++i) {
    const float inv = 1.f / (ec + lc[i]);
    const float4 pv = px4[i];
    pre[i][0] = pv.x + (e0 + l0[i]) * inv;
    pre[i][1] = pv.y + (e1 + l1[i]) * inv;
    pre[i][2] = pv.z + (e2 + l2[i]) * inv;
    pre[i][3] = pv.w + (e3 + l3[i]) * inv;
    mx0 = fmaxf(mx0, pre[i][0]); mx1 = fmaxf(mx1, pre[i][1]);
    mx2 = fmaxf(mx2, pre[i][2]); mx3 = fmaxf(mx3, pre[i][3]);
  }

  #pragma unroll
  for (int off = 32; off; off >>= 1) {
    mx0 = fmaxf(mx0, __shfl_xor(mx0, off, 64));
    mx1 = fmaxf(mx1, __shfl_xor(mx1, off, 64));
    mx2 = fmaxf(mx2, __shfl_xor(mx2, off, 64));
    mx3 = fmaxf(mx3, __shfl_xor(mx3, off, 64));
  }
  if (lane == 0) { smx[wv][0] = mx0; smx[wv][1] = mx1; smx[wv][2] = mx2; smx[wv][3] = mx3; }
  __syncthreads();
  const float M0 = fmaxf(fmaxf(smx[0][0], smx[1][0]), fmaxf(smx[2][0], smx[3][0]));
  const float M1 = fmaxf(fmaxf(smx[0][1], smx[1][1]), fmaxf(smx[2][1], smx[3][1]));
  const float M2 = fmaxf(fmaxf(smx[0][2], smx[1][2]), fmaxf(smx[2][2], smx[3][2]));
  const float M3 = fmaxf(fmaxf(smx[0][3], smx[1][3]), fmaxf(smx[2][3], smx[3][3]));

  float* eB = ws + OFF_EXPW + (size_t)b * P_ * 4;
  float4* e4 = (float4*)(eB + (size_t)p0 * 4);
  #pragma unroll
  for (int i = 0; i < 4; ++i) {
    float4 ev;
    ev.x = __expf(pre[i][0] - M0);
    ev.y = __expf(pre[i][1] - M1);
    ev.z = __expf(pre[i][2] - M2);
    ev.w = __expf(pre[i][3] - M3);
    e4[i] = ev;
  }
}

// ---------- K4a: per-chunk plain sums of (e, e*phi) ----------
__global__ __launch_bounds__(128) void k4a_sums(float* __restrict__ ws) {
  const int ch = blockIdx.x, b = blockIdx.y;
  const int h = threadIdx.x >> 5, d = threadIdx.x & 31;
  const float* eB   = ws + OFF_EXPW + (size_t)b * P_ * 4;
  const float* phiB = ws + OFF_PHI  + (size_t)b * P_ * 32;

  float E = 0.f, S = 0.f;
  const int pbeg = ch * CL_;
  #pragma unroll 4
  for (int p = pbeg; p < pbeg + CL_; ++p) {
    const float e  = eB[p * 4 + h];
    const float ph = phiB[p * 32 + d];
    E += e;
    S = fmaf(e, ph, S);
  }
  const int base = (b * CH_ + ch) * 4 + h;
  if (d == 0) ws[OFF_CE + base] = E;
  ws[OFF_CS + base * 32 + d] = S;
}

// ---------- K45: parallel phase-1 (local replay || staging+prefix) -> combine ----------
__global__ __launch_bounds__(256) void k45_fused(float* __restrict__ ws,
    const void* __restrict__ mask,
    const void* __restrict__ Wrho1, const void* __restrict__ brho1,
    const void* __restrict__ Wrho2, const void* __restrict__ brho2,
    void* __restrict__ out) {
  __shared__ float sW1[8192];       // 32 KB
  __shared__ float sAgg[32][128];   // 16 KB
  __shared__ float sH1[32][64];     //  8 KB
  __shared__ float sEloc[32][4];
  __shared__ float sPreS[128];
  __shared__ float sPreE[4];
  const int ch = blockIdx.x, b = blockIdx.y;
  const int tid = threadIdx.x;
  const bool isf32 = detect_f32(mask);
  const int pbeg = ch * CL_;

  if (tid < 128) {
    const int h = tid >> 5, d = tid & 31;
    const float* eB   = ws + OFF_EXPW + (size_t)b * P_ * 4;
    const float* phiB = ws + OFF_PHI  + (size_t)b * P_ * 32;
    float E = 0.f, S = 0.f;
    #pragma unroll 4
    for (int p = pbeg; p < pbeg + CL_; ++p) {
      const float e  = eB[p * 4 + h];
      const float ph = phiB[p * 32 + d];
      E += e;
      S = fmaf(e, ph, S);
      sAgg[p - pbeg][h * 32 + d] = S;            // unnormalized local S
      if (d == 0) sEloc[p - pbeg][h] = E;        // local inclusive E
    }
  } else {
    const int tt = tid - 128;
    // stage W_rho1 (vectorized 16B loads)
    if (isf32) {
      const float4* w1 = (const float4*)Wrho1;  // 2048 float4
      for (int i = tt; i < 2048; i += 128) {
        const float4 v = w1[i];
        float* dst = sW1 + i * 4;
        dst[0] = v.x; dst[1] = v.y; dst[2] = v.z; dst[3] = v.w;
      }
    } else {
      const uint4* w1 = (const uint4*)Wrho1;    // 1024 uint4 = 8192 bf16
      for (int i = tt; i < 1024; i += 128) {
        const uint4 v = w1[i];
        float* dst = sW1 + i * 8;
        dst[0] = bfbits(v.x & 0xFFFFu); dst[1] = bfbits(v.x >> 16);
        dst[2] = bfbits(v.y & 0xFFFFu); dst[3] = bfbits(v.y >> 16);
        dst[4] = bfbits(v.z & 0xFFFFu); dst[5] = bfbits(v.z >> 16);
        dst[6] = bfbits(v.w & 0xFFFFu); dst[7] = bfbits(v.w >> 16);
      }
    }
    // prefix over earlier chunks for this (h,d) — runs concurrent with local replay
    const int h = tt >> 5, d = tt & 31;
    float E0 = 0.f, S0 = 0.f;
    #pragma unroll 4
    for (int c2 = 0; c2 < ch; ++c2) {
      const int base2 = (b * CH_ + c2) * 4 + h;
      E0 += ws[OFF_CE + base2];
      S0 += ws[OFF_CS + base2 * 32 + d];
    }
    sPreS[tt] = S0;
    if (d == 0) sPreE[h] = E0;
  }
  __syncthreads();

  // combine: 4096 slots / 256 threads = 16 each (stride-256, conflict-free)
  #pragma unroll
  for (int k = 0; k < 16; ++k) {
    const int slot = tid + k * 256;
    const int p = slot >> 7, c = slot & 127, h2 = c >> 5;
    const float Et = sPreE[h2] + sEloc[p][h2];
    const float St = sPreS[c] + sAgg[p][c];
    sAgg[p][c] = (St / Et) * ld_any(mask, b * P_ + pbeg + p, isf32);
  }
  __syncthreads();

  // phase 2: rho L1, each wave owns 8 tokens
  const int j = tid & 63, qw = tid >> 6;
  const float b1 = ld_any(brho1, j, isf32);
  float acc[8];
  #pragma unroll
  for (int k = 0; k < 8; ++k) acc[k] = b1;
  for (int i4 = 0; i4 < 32; ++i4) {
    const float w0 = sW1[(i4 * 4 + 0) * 64 + j];
    const float w1 = sW1[(i4 * 4 + 1) * 64 + j];
    const float w2 = sW1[(i4 * 4 + 2) * 64 + j];
    const float w3 = sW1[(i4 * 4 + 3) * 64 + j];
    #pragma unroll
    for (int k = 0; k < 8; ++k) {
      const float4 a = *(const float4*)&sAgg[qw * 8 + k][i4 * 4];
      acc[k] = fmaf(a.w, w3, fmaf(a.z, w2, fmaf(a.y, w1, fmaf(a.x, w0, acc[k]))));
    }
  }
  #pragma unroll
  for (int k = 0; k < 8; ++k) sH1[qw * 8 + k][j] = fmaxf(acc[k], 0.f);
  __syncthreads();

  // phase 3: rho L2 (W2 direct from raw; branch hoisted out of the loop)
  const float b2 = ld_any(brho2, j, isf32);
  float o[8];
  #pragma unroll
  for (int k = 0; k < 8; ++k) o[k] = b2;
  if (isf32) {
    const float* W2 = (const float*)Wrho2;
    #pragma unroll 4
    for (int i = 0; i < 64; ++i) {
      const float w = W2[i * 64 + j];
      #pragma unroll
      for (int k = 0; k < 8; ++k) o[k] = fmaf(sH1[qw * 8 + k][i], w, o[k]);
    }
  } else {
    const __hip_bfloat16* W2 = (const __hip_bfloat16*)Wrho2;
    #pragma unroll 4
    for (int i = 0; i < 64; ++i) {
      const float w = __bfloat162float(W2[i * 64 + j]);
      #pragma unroll
      for (int k = 0; k < 8; ++k) o[k] = fmaf(sH1[qw * 8 + k][i], w, o[k]);
    }
  }

  const int t0 = b * P_ + pbeg + qw * 8;
  #pragma unroll
  for (int k = 0; k < 8; ++k) {
    const float mv = ld_any(mask, t0 + k, isf32);
    const float v  = fmaxf(o[k], 0.f) * mv;
    if (isf32) {
      ((float*)out)[(size_t)(t0 + k) * 64 + j] = v;
    } else {
      ((__hip_bfloat16*)out)[(size_t)(t0 + k) * 64 + j] = __float2bfloat16(v);
    }
  }
}

extern "C" void kernel_launch(void* const* d_in, const int* in_sizes, int n_in,
                              void* d_out, int out_size, void* d_ws, size_t ws_size,
                              hipStream_t stream) {
  const int* meas = (const int*)d_in[2];
  const void* times = d_in[0];
  const void* values = d_in[1];
  const void* mask = d_in[3];
  float* ws = (float*)d_ws;

  s01_prep<<<10, 256, 0, stream>>>(ws, mask,
                                   d_in[4], d_in[5], d_in[6], d_in[7],
                                   d_in[8], d_in[9], d_in[10],
                                   d_in[11], d_in[12], d_in[13], d_in[14]);
  k1_token<<<T_/32, 1024, 0, stream>>>(ws, meas, times, values, mask);
  k2_scanz<<<B_, 256, 0, stream>>>(ws, mask);
  k4a_sums<<<dim3(CH_, B_), 128, 0, stream>>>(ws);
  k45_fused<<<dim3(CH_, B_), 256, 0, stream>>>(ws, mask,
                                               d_in[15], d_in[16], d_in[17], d_in[18],
                                               d_out);
}